// Round 3
// baseline (785.262 us; speedup 1.0000x reference)
//
#include <hip/hip_runtime.h>

// 32 chained bottleneck blocks on x[16,256,64,64] fp32.
// Phase A: h1_0 = relu(W1_0 x + b1_0)           (reads x once)
// Phase B (x32): h2_k = relu(conv3x3 h1_k), store h2_k;
//                h1_{k+1} = relu(W1_{k+1} relu(W3_k h2_k + b3_k) + b1_{k+1})
// Phase C: out = sum_k relu(W3_k h2_k + b3_k)
//
// R9 (= R8 retry at proven 34.0 MiB workspace): both B and C were
// LDS-read-bound (B expand: 32 ds_read_b128/thread; C: 1:1 LDS:VALU cycle
// ratio). Rework: lane = pixel, channel slice = wave-uniform
// (readfirstlane) -> all weights via s_load (SQC scalar path, zero LDS).
// phaseB: conv reads h1 straight from global (L2-hot, no tile staging,
// 2 barriers; block-uniform border branch with clamp+select); expand
// iterates 64ch/wave reading w3/w1^T directly (no packing kernel).
// phaseC: acc[64]/lane, 1 ds_read_b128 per k per lane, barrier per 4 k.

#define NN 16
#define HH 64
#define WW 64
#define CIN 256
#define CB 4
#define NBLK 32

// bijective 64-px swizzle: spreads stride-16B float4 access over all banks
__device__ __forceinline__ int swz64(int i) { return i ^ ((i >> 3) & 7); }

// ---------------- Phase A: h1_0 = relu(W1_0 . x + b1_0) ------------------
// grid (64,16): blockIdx.x = y, blockIdx.y = n. 256 threads.
__global__ __launch_bounds__(256) void phaseA(
    const float* __restrict__ x, const float* __restrict__ w1,
    const float* __restrict__ b1, float* __restrict__ h1out) {
  __shared__ float4 w1s[CIN];    // [c] -> o components
  __shared__ float4 part[4][WW]; // [chunk][px] -> o components
  int tid = threadIdx.x;
  for (int i = tid; i < CIN * CB; i += 256) {
    int o = i >> 8, c = i & 255;
    ((float*)&w1s[c])[o] = w1[i]; // w1 global layout [o][c]
  }
  __syncthreads();
  int y = blockIdx.x, n = blockIdx.y;
  int chunk = tid >> 6, px = tid & 63;
  int cbase = chunk * 64;
  const float* xp = x + ((n * CIN + cbase) * HH + y) * WW + px;
  float s0 = 0.f, s1 = 0.f, s2 = 0.f, s3 = 0.f;
#pragma unroll 8
  for (int i = 0; i < 64; ++i) {
    float xv = xp[i * HH * WW];
    float4 wv = w1s[cbase + i];
    s0 = fmaf(xv, wv.x, s0);
    s1 = fmaf(xv, wv.y, s1);
    s2 = fmaf(xv, wv.z, s2);
    s3 = fmaf(xv, wv.w, s3);
  }
  part[chunk][px] = make_float4(s0, s1, s2, s3);
  __syncthreads();
  int px2 = tid >> 2, o = tid & 3;
  float v = ((float*)&part[0][px2])[o] + ((float*)&part[1][px2])[o] +
            ((float*)&part[2][px2])[o] + ((float*)&part[3][px2])[o];
  v += b1[o];
  h1out[((n * HH + y) * WW + px2) * CB + o] = fmaxf(v, 0.f);
}

// ---------------- Phase B: one bottleneck step ---------------------------
// 8x8 tile, 256 threads, grid (8,8,16) = 1024 blocks = 4/CU.
// lane = pixel; wave wv: conv oc = wv, expand ch slice [64wv,64wv+64).
// All weights via wave-uniform s_load. 2 barriers.
__global__ __launch_bounds__(256, 4) void phaseB(
    const float* __restrict__ h1in, float* __restrict__ h1out,
    float* __restrict__ h2out,
    const float* __restrict__ w2k,   // w2 + k*144, [oc][ic][3][3]
    const float* __restrict__ b2k,   // b2 + k*4
    const float* __restrict__ w3k,   // w3 + k*1024, [c][j]
    const float* __restrict__ b3k,   // b3 + k*256
    const float* __restrict__ w1n,   // w1 + kn*1024, [o][c]
    const float* __restrict__ b1n,   // b1 + kn*4
    int compute_next) {
  __shared__ float h2sb[4][64];   // [oc][px]           1 KB
  __shared__ float4 comb[4][64];  // [wave][px] partial 4 KB
  int tid = threadIdx.x;
  int lane = tid & 63;
  int wvu = __builtin_amdgcn_readfirstlane(tid >> 6);
  int x0 = blockIdx.x * 8, y0 = blockIdx.y * 8, n = blockIdx.z;
  int lx = lane & 7, ly = lane >> 3;
  int gy = y0 + ly, gx = x0 + lx;

  // --- conv 3x3 (4->4) + bias + relu; oc = wvu, one px per lane ---------
  float4 win[9];
  bool interior = (x0 > 0) && (x0 < WW - 8) && (y0 > 0) && (y0 < HH - 8);
  if (interior) { // block-uniform branch, no divergence
    const float* hp = h1in + ((n * HH + gy - 1) * WW + gx - 1) * CB;
#pragma unroll
    for (int dy = 0; dy < 3; ++dy)
#pragma unroll
      for (int dx = 0; dx < 3; ++dx)
        win[dy * 3 + dx] = *(const float4*)(hp + (dy * WW + dx) * CB);
  } else {
#pragma unroll
    for (int dy = 0; dy < 3; ++dy) {
      int ry = gy - 1 + dy;
      bool vy = (ry >= 0) && (ry < HH);
      int ryc = vy ? ry : 0;
#pragma unroll
      for (int dx = 0; dx < 3; ++dx) {
        int rx = gx - 1 + dx;
        bool vx = (rx >= 0) && (rx < WW);
        int rxc = vx ? rx : 0;
        float4 v = *(const float4*)&h1in[((n * HH + ryc) * WW + rxc) * CB];
        if (!(vy && vx)) v = make_float4(0.f, 0.f, 0.f, 0.f);
        win[dy * 3 + dx] = v;
      }
    }
  }
  const float* w2w = w2k + wvu * 36;   // uniform -> s_load
  float hacc = b2k[wvu];
#pragma unroll
  for (int p = 0; p < 9; ++p) {
    hacc = fmaf(win[p].x, w2w[0 + p], hacc);
    hacc = fmaf(win[p].y, w2w[9 + p], hacc);
    hacc = fmaf(win[p].z, w2w[18 + p], hacc);
    hacc = fmaf(win[p].w, w2w[27 + p], hacc);
  }
  h2sb[wvu][lane] = fmaxf(hacc, 0.f);
  __syncthreads(); // B1: h2 tile ready

  // gather own pixel's 4 channels (2 lanes/bank b32 reads: free)
  float4 h;
  h.x = h2sb[0][lane];
  h.y = h2sb[1][lane];
  h.z = h2sb[2][lane];
  h.w = h2sb[3][lane];
  if (tid < 64) // coalesced float4 h2 store for phaseC
    *(float4*)&h2out[((n * HH + gy) * WW + gx) * CB] = h;

  if (!compute_next) return; // last step: expand handled by phaseC

  // --- fused expand(W3)+relu+reduce(W1_next): 64 ch per wave, SGPR wts --
  float4 tp = make_float4(0.f, 0.f, 0.f, 0.f);
  const float* w3r = w3k + wvu * 256;        // [cc][4], uniform
  const float* b3r = b3k + wvu * 64;         // uniform
  const float* w1r0 = w1n + 0 * 256 + wvu * 64;
  const float* w1r1 = w1n + 1 * 256 + wvu * 64;
  const float* w1r2 = w1n + 2 * 256 + wvu * 64;
  const float* w1r3 = w1n + 3 * 256 + wvu * 64;
#pragma unroll
  for (int cc = 0; cc < 64; ++cc) {
    float u = b3r[cc];
    u = fmaf(h.x, w3r[cc * 4 + 0], u);
    u = fmaf(h.y, w3r[cc * 4 + 1], u);
    u = fmaf(h.z, w3r[cc * 4 + 2], u);
    u = fmaf(h.w, w3r[cc * 4 + 3], u);
    float v = fmaxf(u, 0.f);
    tp.x = fmaf(v, w1r0[cc], tp.x);
    tp.y = fmaf(v, w1r1[cc], tp.y);
    tp.z = fmaf(v, w1r2[cc], tp.z);
    tp.w = fmaf(v, w1r3[cc], tp.w);
  }
  comb[wvu][swz64(lane)] = tp;
  __syncthreads(); // B2: partials staged

  if (tid < 64) {
    int m = swz64(lane);
    float4 t0 = comb[0][m], t1 = comb[1][m], t2 = comb[2][m], t3 = comb[3][m];
    float4 r;
    r.x = fmaxf(t0.x + t1.x + t2.x + t3.x + b1n[0], 0.f);
    r.y = fmaxf(t0.y + t1.y + t2.y + t3.y + b1n[1], 0.f);
    r.z = fmaxf(t0.z + t1.z + t2.z + t3.z + b1n[2], 0.f);
    r.w = fmaxf(t0.w + t1.w + t2.w + t3.w + b1n[3], 0.f);
    *(float4*)&h1out[((n * HH + gy) * WW + gx) * CB] = r;
  }
}

// ---------------- Phase C: acc = sum_k relu(W3_k h2_k + b3_k) ------------
// Block = 64 px x 256 ch. Wave wv owns ch [64wv,64wv+64); lane = px with
// acc[64] in VGPRs. Weights via wave-uniform s_load. Per k per lane: ONE
// swizzled ds_read_b128. 4-deep h2 staging, barrier per 4 k. grid (64,16).
__global__ __launch_bounds__(256, 4) void phaseC(
    const float* __restrict__ h2buf, const float* __restrict__ w3g,
    const float* __restrict__ b3g, float* __restrict__ out) {
  __shared__ float4 h2s[8][64];   // 2 groups x 4 k x 64 px   8 KB
  __shared__ float tr[64][68];    // transpose chunk          17.4 KB
  int tid = threadIdx.x;
  int lane = tid & 63;
  int wvu = __builtin_amdgcn_readfirstlane(tid >> 6);
  int p0 = blockIdx.x * 64;
  int n = blockIdx.y;

  float acc[64];
#pragma unroll
  for (int i = 0; i < 64; ++i) acc[i] = 0.f;

  // prologue: stage group 0 (k=0..3); wave kk stages buffer kk, px=lane
  {
    int kk = tid >> 6;
    h2s[kk][swz64(lane)] =
        *(const float4*)&h2buf[((kk * NN + n) * 4096 + p0 + lane) * 4];
  }
  __syncthreads();

  for (int g = 0; g < 8; ++g) {
    if (g < 7) { // stage group g+1 into other half (disjoint slots)
      int kk = tid >> 6;
      int k = (g + 1) * 4 + kk;
      h2s[(((g + 1) & 1) << 2) + kk][swz64(lane)] =
          *(const float4*)&h2buf[((k * NN + n) * 4096 + p0 + lane) * 4];
    }
#pragma unroll
    for (int kk = 0; kk < 4; ++kk) {
      int k = g * 4 + kk;
      float4 h = h2s[((g & 1) << 2) + kk][swz64(lane)];
      const float* wrow = w3g + (k * 256 + wvu * 64) * 4; // uniform
      const float* brow = b3g + k * 256 + wvu * 64;       // uniform
#pragma unroll
      for (int cc = 0; cc < 64; ++cc) {
        float u = brow[cc];
        u = fmaf(h.x, wrow[cc * 4 + 0], u);
        u = fmaf(h.y, wrow[cc * 4 + 1], u);
        u = fmaf(h.z, wrow[cc * 4 + 2], u);
        u = fmaf(h.w, wrow[cc * 4 + 3], u);
        acc[cc] += fmaxf(u, 0.f);
      }
    }
    __syncthreads(); // group staged & consumed
  }

  // transpose in 4 chunks of 64 channels (one wave's slice each)
  int r = tid >> 2, c4 = (tid & 3) * 16;
  for (int ch = 0; ch < 4; ++ch) {
    if (wvu == ch) {
#pragma unroll
      for (int cc = 0; cc < 64; ++cc) tr[cc][lane] = acc[cc]; // 2 lanes/bank
    }
    __syncthreads();
#pragma unroll
    for (int j = 0; j < 4; ++j) {
      float4 v = *(const float4*)&tr[r][c4 + j * 4];
      *(float4*)&out[(n * CIN + ch * 64 + r) * (HH * WW) + p0 + c4 + j * 4] = v;
    }
    __syncthreads();
  }
}

extern "C" void kernel_launch(void* const* d_in, const int* in_sizes, int n_in,
                              void* d_out, int out_size, void* d_ws, size_t ws_size,
                              hipStream_t stream) {
  const float* x  = (const float*)d_in[0];
  const float* w1 = (const float*)d_in[1]; // [32][4][256]
  const float* b1 = (const float*)d_in[2]; // [32][4]
  const float* w2 = (const float*)d_in[3]; // [32][4][4][3][3]
  const float* b2 = (const float*)d_in[4]; // [32][4]
  const float* w3 = (const float*)d_in[5]; // [32][256][4]
  const float* b3 = (const float*)d_in[6]; // [32][256]
  float* out = (float*)d_out;
  float* ws = (float*)d_ws;

  const int STATE = NN * HH * WW * CB; // 262144 floats = 1 MiB
  float* h1a = ws;
  float* h1b = ws + STATE;
  float* h2  = ws + 2 * STATE; // 32 MiB -> total 34 MiB (proven footprint)

  phaseA<<<dim3(HH, NN), 256, 0, stream>>>(x, w1, b1, h1a);
  for (int k = 0; k < NBLK; ++k) {
    const float* hin = (k & 1) ? h1b : h1a;
    float* hout = (k & 1) ? h1a : h1b;
    int kn = (k < NBLK - 1) ? k + 1 : NBLK - 1; // wrapped, unused on last
    phaseB<<<dim3(8, 8, NN), 256, 0, stream>>>(
        hin, hout, h2 + k * STATE,
        w2 + k * 144, b2 + k * CB, w3 + k * 1024, b3 + k * 256,
        w1 + kn * 1024, b1 + kn * CB, (k < NBLK - 1) ? 1 : 0);
  }
  phaseC<<<dim3((HH * WW) / 64, NN), 256, 0, stream>>>(h2, w3, b3, out);
}

// Round 4
// 586.203 us; speedup vs baseline: 1.3396x; 1.3396x over previous
//
#include <hip/hip_runtime.h>

// 32 chained bottleneck blocks on x[16,256,64,64] fp32.
// Phase A: h1_0 = relu(W1_0 x + b1_0)           (reads x once)
// Phase B (x32): h2_k = relu(conv3x3 h1_k), store h2_k;
//                h1_{k+1} = relu(W1_{k+1} relu(W3_k h2_k + b3_k) + b1_{k+1})
// Phase C: out = sum_k relu(W3_k h2_k + b3_k)
//
// R10: R9's 785us was VGPR spill under __launch_bounds__(256,4): phaseC
// VGPR capped at 64 with acc[64] needing ~100 -> ~1GB scratch traffic per
// dispatch (FETCH 329MB/WRITE 674MB, VALUBusy 28%). Fix: size registers to
// the cap. phaseC: 64px x 128ch blocks -> acc[32]/thread, no LDS, lane=px
// direct-coalesced stores from regs, h2 reg-prefetch from global (L2/L3),
// weights on scalar path. phaseB: rolling 3-row conv (<=3 live float4),
// bounds (256,2) everywhere register pressure matters.

#define NN 16
#define HH 64
#define WW 64
#define CIN 256
#define CB 4
#define NBLK 32

// bijective 64-px swizzle: spreads stride-16B float4 access over all banks
__device__ __forceinline__ int swz64(int i) { return i ^ ((i >> 3) & 7); }

// ---------------- Phase A: h1_0 = relu(W1_0 . x + b1_0) ------------------
// grid (64,16): blockIdx.x = y, blockIdx.y = n. 256 threads.
__global__ __launch_bounds__(256) void phaseA(
    const float* __restrict__ x, const float* __restrict__ w1,
    const float* __restrict__ b1, float* __restrict__ h1out) {
  __shared__ float4 w1s[CIN];    // [c] -> o components
  __shared__ float4 part[4][WW]; // [chunk][px] -> o components
  int tid = threadIdx.x;
  for (int i = tid; i < CIN * CB; i += 256) {
    int o = i >> 8, c = i & 255;
    ((float*)&w1s[c])[o] = w1[i]; // w1 global layout [o][c]
  }
  __syncthreads();
  int y = blockIdx.x, n = blockIdx.y;
  int chunk = tid >> 6, px = tid & 63;
  int cbase = chunk * 64;
  const float* xp = x + ((n * CIN + cbase) * HH + y) * WW + px;
  float s0 = 0.f, s1 = 0.f, s2 = 0.f, s3 = 0.f;
#pragma unroll 8
  for (int i = 0; i < 64; ++i) {
    float xv = xp[i * HH * WW];
    float4 wv = w1s[cbase + i];
    s0 = fmaf(xv, wv.x, s0);
    s1 = fmaf(xv, wv.y, s1);
    s2 = fmaf(xv, wv.z, s2);
    s3 = fmaf(xv, wv.w, s3);
  }
  part[chunk][px] = make_float4(s0, s1, s2, s3);
  __syncthreads();
  int px2 = tid >> 2, o = tid & 3;
  float v = ((float*)&part[0][px2])[o] + ((float*)&part[1][px2])[o] +
            ((float*)&part[2][px2])[o] + ((float*)&part[3][px2])[o];
  v += b1[o];
  h1out[((n * HH + y) * WW + px2) * CB + o] = fmaxf(v, 0.f);
}

// ---------------- Phase B: one bottleneck step ---------------------------
// 8x8 tile, 256 threads, grid (8,8,16) = 1024 blocks = 4/CU.
// lane = pixel; wave wv: conv oc = wv, expand ch slice [64wv,64wv+64).
// All weights via wave-uniform s_load. 2 barriers.
__global__ __launch_bounds__(256, 2) void phaseB(
    const float* __restrict__ h1in, float* __restrict__ h1out,
    float* __restrict__ h2out,
    const float* __restrict__ w2k,   // w2 + k*144, [oc][ic][3][3]
    const float* __restrict__ b2k,   // b2 + k*4
    const float* __restrict__ w3k,   // w3 + k*1024, [c][j]
    const float* __restrict__ b3k,   // b3 + k*256
    const float* __restrict__ w1n,   // w1 + kn*1024, [o][c]
    const float* __restrict__ b1n,   // b1 + kn*4
    int compute_next) {
  __shared__ float h2sb[4][64];   // [oc][px]           1 KB
  __shared__ float4 comb[4][64];  // [wave][px] partial 4 KB
  int tid = threadIdx.x;
  int lane = tid & 63;
  int wvu = __builtin_amdgcn_readfirstlane(tid >> 6);
  int x0 = blockIdx.x * 8, y0 = blockIdx.y * 8, n = blockIdx.z;
  int lx = lane & 7, ly = lane >> 3;
  int gy = y0 + ly, gx = x0 + lx;

  // --- conv 3x3 (4->4) + bias + relu; oc = wvu, one px per lane ---------
  // rolling per-row accumulation: <=3 float4 live at a time
  const float* w2w = w2k + wvu * 36;   // uniform -> s_load
  float hacc0 = b2k[wvu], hacc1 = 0.f, hacc2 = 0.f;
  bool interior = (x0 > 0) && (x0 < WW - 8) && (y0 > 0) && (y0 < HH - 8);
  if (interior) { // block-uniform branch, no divergence
    const float* hp = h1in + ((n * HH + gy - 1) * WW + gx - 1) * CB;
#pragma unroll
    for (int dy = 0; dy < 3; ++dy) {
      const float* hr = hp + dy * WW * CB;
      float4 a = *(const float4*)hr;
      float4 b = *(const float4*)(hr + CB);
      float4 c = *(const float4*)(hr + 2 * CB);
      int p = dy * 3;
      hacc0 = fmaf(a.x, w2w[p], hacc0);
      hacc0 = fmaf(a.y, w2w[9 + p], hacc0);
      hacc0 = fmaf(a.z, w2w[18 + p], hacc0);
      hacc0 = fmaf(a.w, w2w[27 + p], hacc0);
      hacc1 = fmaf(b.x, w2w[p + 1], hacc1);
      hacc1 = fmaf(b.y, w2w[9 + p + 1], hacc1);
      hacc1 = fmaf(b.z, w2w[18 + p + 1], hacc1);
      hacc1 = fmaf(b.w, w2w[27 + p + 1], hacc1);
      hacc2 = fmaf(c.x, w2w[p + 2], hacc2);
      hacc2 = fmaf(c.y, w2w[9 + p + 2], hacc2);
      hacc2 = fmaf(c.z, w2w[18 + p + 2], hacc2);
      hacc2 = fmaf(c.w, w2w[27 + p + 2], hacc2);
    }
  } else {
#pragma unroll
    for (int dy = 0; dy < 3; ++dy) {
      int ry = gy - 1 + dy;
      bool vy = (ry >= 0) && (ry < HH);
      const float* hr = h1in + ((n * HH + (vy ? ry : 0)) * WW) * CB;
#pragma unroll
      for (int dx = 0; dx < 3; ++dx) {
        int rx = gx - 1 + dx;
        bool vx = (rx >= 0) && (rx < WW);
        float4 v = *(const float4*)&hr[(vx ? rx : 0) * CB];
        if (!(vy && vx)) v = make_float4(0.f, 0.f, 0.f, 0.f);
        int p = dy * 3 + dx;
        hacc0 = fmaf(v.x, w2w[p], hacc0);
        hacc0 = fmaf(v.y, w2w[9 + p], hacc0);
        hacc1 = fmaf(v.z, w2w[18 + p], hacc1);
        hacc2 = fmaf(v.w, w2w[27 + p], hacc2);
      }
    }
  }
  h2sb[wvu][lane] = fmaxf(hacc0 + hacc1 + hacc2, 0.f);
  __syncthreads(); // B1: h2 tile ready

  // gather own pixel's 4 channels (2 lanes/bank b32 reads: free)
  float4 h;
  h.x = h2sb[0][lane];
  h.y = h2sb[1][lane];
  h.z = h2sb[2][lane];
  h.w = h2sb[3][lane];
  if (tid < 64) // coalesced float4 h2 store for phaseC
    *(float4*)&h2out[((n * HH + gy) * WW + gx) * CB] = h;

  if (!compute_next) return; // last step: expand handled by phaseC

  // --- fused expand(W3)+relu+reduce(W1_next): 64 ch per wave, SGPR wts --
  float4 tp = make_float4(0.f, 0.f, 0.f, 0.f);
  const float* w3r = w3k + wvu * 256;        // [cc][4], uniform
  const float* b3r = b3k + wvu * 64;         // uniform
  const float* w1r0 = w1n + 0 * 256 + wvu * 64;
  const float* w1r1 = w1n + 1 * 256 + wvu * 64;
  const float* w1r2 = w1n + 2 * 256 + wvu * 64;
  const float* w1r3 = w1n + 3 * 256 + wvu * 64;
#pragma unroll
  for (int cc = 0; cc < 64; ++cc) {
    float u = b3r[cc];
    u = fmaf(h.x, w3r[cc * 4 + 0], u);
    u = fmaf(h.y, w3r[cc * 4 + 1], u);
    u = fmaf(h.z, w3r[cc * 4 + 2], u);
    u = fmaf(h.w, w3r[cc * 4 + 3], u);
    float v = fmaxf(u, 0.f);
    tp.x = fmaf(v, w1r0[cc], tp.x);
    tp.y = fmaf(v, w1r1[cc], tp.y);
    tp.z = fmaf(v, w1r2[cc], tp.z);
    tp.w = fmaf(v, w1r3[cc], tp.w);
  }
  comb[wvu][swz64(lane)] = tp;
  __syncthreads(); // B2: partials staged

  if (tid < 64) {
    int m = swz64(lane);
    float4 t0 = comb[0][m], t1 = comb[1][m], t2 = comb[2][m], t3 = comb[3][m];
    float4 r;
    r.x = fmaxf(t0.x + t1.x + t2.x + t3.x + b1n[0], 0.f);
    r.y = fmaxf(t0.y + t1.y + t2.y + t3.y + b1n[1], 0.f);
    r.z = fmaxf(t0.z + t1.z + t2.z + t3.z + b1n[2], 0.f);
    r.w = fmaxf(t0.w + t1.w + t2.w + t3.w + b1n[3], 0.f);
    *(float4*)&h1out[((n * HH + gy) * WW + gx) * CB] = r;
  }
}

// ---------------- Phase C: acc = sum_k relu(W3_k h2_k + b3_k) ------------
// Block = 64 px x 128 ch (acc[32]/thread, no spill). Lane = px; wave wv
// owns 32 uniform channels -> weights via s_load. h2[k][px] loaded straight
// from global (L2/L3-hot), reg-prefetched one k ahead. No LDS, no barriers;
// stores coalesced directly from registers. grid (128,16) = 2048 blocks.
__global__ __launch_bounds__(256, 2) void phaseC(
    const float* __restrict__ h2buf, const float* __restrict__ w3g,
    const float* __restrict__ b3g, float* __restrict__ out) {
  int tid = threadIdx.x;
  int lane = tid & 63;
  int wvu = __builtin_amdgcn_readfirstlane(tid >> 6);
  int bx = blockIdx.x;
  int p0 = (bx >> 1) * 64;            // px tile (adjacent blocks share it)
  int cb = (bx & 1) * 128 + wvu * 32; // wave's channel base (uniform)
  int n = blockIdx.y;

  float acc[32];
#pragma unroll
  for (int i = 0; i < 32; ++i) acc[i] = 0.f;

  float4 h = *(const float4*)&h2buf[((0 * NN + n) * 4096 + p0 + lane) * 4];
  for (int k = 0; k < NBLK; ++k) {
    float4 hn = h;
    if (k + 1 < NBLK) // prefetch next k while this k's 192 FMAs run
      hn = *(const float4*)&h2buf[(((k + 1) * NN + n) * 4096 + p0 + lane) * 4];
    const float* wrow = w3g + (k * 256 + cb) * 4; // uniform -> s_load
    const float* brow = b3g + k * 256 + cb;       // uniform -> s_load
#pragma unroll
    for (int cc = 0; cc < 32; ++cc) {
      float u = brow[cc];
      u = fmaf(h.x, wrow[cc * 4 + 0], u);
      u = fmaf(h.y, wrow[cc * 4 + 1], u);
      u = fmaf(h.z, wrow[cc * 4 + 2], u);
      u = fmaf(h.w, wrow[cc * 4 + 3], u);
      acc[cc] += fmaxf(u, 0.f);
    }
    h = hn;
  }

  // lane = px: 256 B contiguous per wave-store, no transpose needed
#pragma unroll
  for (int cc = 0; cc < 32; ++cc)
    out[(n * CIN + cb + cc) * (HH * WW) + p0 + lane] = acc[cc];
}

extern "C" void kernel_launch(void* const* d_in, const int* in_sizes, int n_in,
                              void* d_out, int out_size, void* d_ws, size_t ws_size,
                              hipStream_t stream) {
  const float* x  = (const float*)d_in[0];
  const float* w1 = (const float*)d_in[1]; // [32][4][256]
  const float* b1 = (const float*)d_in[2]; // [32][4]
  const float* w2 = (const float*)d_in[3]; // [32][4][4][3][3]
  const float* b2 = (const float*)d_in[4]; // [32][4]
  const float* w3 = (const float*)d_in[5]; // [32][256][4]
  const float* b3 = (const float*)d_in[6]; // [32][256]
  float* out = (float*)d_out;
  float* ws = (float*)d_ws;

  const int STATE = NN * HH * WW * CB; // 262144 floats = 1 MiB
  float* h1a = ws;
  float* h1b = ws + STATE;
  float* h2  = ws + 2 * STATE; // 32 MiB -> total 34 MiB (proven footprint)

  phaseA<<<dim3(HH, NN), 256, 0, stream>>>(x, w1, b1, h1a);
  for (int k = 0; k < NBLK; ++k) {
    const float* hin = (k & 1) ? h1b : h1a;
    float* hout = (k & 1) ? h1a : h1b;
    int kn = (k < NBLK - 1) ? k + 1 : NBLK - 1; // wrapped, unused on last
    phaseB<<<dim3(8, 8, NN), 256, 0, stream>>>(
        hin, hout, h2 + k * STATE,
        w2 + k * 144, b2 + k * CB, w3 + k * 1024, b3 + k * 256,
        w1 + kn * 1024, b1 + kn * CB, (k < NBLK - 1) ? 1 : 0);
  }
  phaseC<<<dim3(2 * (HH * WW) / 64, NN), 256, 0, stream>>>(h2, w3, b3, out);
}